// Round 14
// baseline (303.535 us; speedup 1.0000x reference)
//
#include <hip/hip_runtime.h>

// Problem dims (fixed by the reference): B=256, T=100, D=1024, H=128, C=5
constexpr int Bsz = 256;
constexpr int Tn  = 100;
constexpr int Dn  = 1024;
constexpr int Hn  = 128;
constexpr int Cn  = 5;

// float64 values of np.exp(-1/10), np.exp(-1/20)
#define D1 0.9048374180359595731642491
#define D2 0.9512294245007140090914253

typedef short  bf16x8 __attribute__((ext_vector_type(8)));
typedef short  short4v __attribute__((ext_vector_type(4)));
typedef float  f32x4  __attribute__((ext_vector_type(4)));

// ---------------------------------------------------------------------------
// R22: two-level load pipeline on R21's proven 3xbf16 structure.
// R21 post-mortem: gemm 131us with MfmaUtil 12 / VALUBusy 11 / HBM 9% —
// all pipes idle. MFMA content is ~20us; the rest is naked load latency:
// each K=32 chunk starts with 6 L2 B-fragment loads that the first MFMA
// waits on (~200-400cy, every chunk), and the X prefetch (depth-1, ~900cy
// HBM) is marginally covered. The f64 kernel hid these under slow f64
// MFMAs; bf16 MFMAs are too fast. Fixes (numerics bit-identical):
//  1. B chunk-level double buffer (static bA/bB, kc-unrolled): chunk g's
//     fragments load during chunk g-1's MFMAs (+48 VGPR).
//  2. X prefetch depth-2 sub-chunks (pf[2][2]): load-to-use = 2 barrier
//     periods (~1500cy) > 900cy HBM latency.
// Failure read: gemm >=120 with MfmaUtil ~12 => request-rate bound, not
// latency => stage B via LDS next. VGPR>110 + occupancy<20 => reg bite.
// ---------------------------------------------------------------------------
constexpr int TILE_M = 32;
constexpr int SC     = 64;            // staging sub-chunk (k)
constexpr int NSUB   = Dn / SC;       // 16
constexpr int NCHUNK = 2;             // K=32 MFMA chunks per sub-chunk

__device__ __forceinline__ unsigned f2b_bits(float f) {
  union { float f; unsigned u; } c; c.f = f;
  return (c.u + 0x7FFFu + ((c.u >> 16) & 1u)) >> 16;   // RNE f32->bf16
}
__device__ __forceinline__ float b_bits2f(unsigned b) {
  union { unsigned u; float f; } c; c.u = b << 16; return c.f;
}

// ---------------------------------------------------------------------------
// W1 f32 -> 3 transposed bf16 planes W1sT[3][Hn][Dn] (exact split) — proven
// ---------------------------------------------------------------------------
__global__ __launch_bounds__(256) void cvt_w1_split(const float* __restrict__ W1,
                                                    short* __restrict__ W1sT)
{
  const int n  = blockIdx.x;              // 0..127
  const int k0 = threadIdx.x * 4;         // 0..1020
  short4v s0, s1, s2;
  #pragma unroll
  for (int j = 0; j < 4; ++j) {
    const float x = W1[(size_t)(k0 + j) * Hn + n];
    const unsigned u0 = f2b_bits(x);  const float f0 = b_bits2f(u0);
    const float r1 = x - f0;
    const unsigned u1 = f2b_bits(r1); const float f1 = b_bits2f(u1);
    const float r2 = r1 - f1;
    const unsigned u2 = f2b_bits(r2);
    s0[j] = (short)u0; s1[j] = (short)u1; s2[j] = (short)u2;
  }
  const size_t PL = (size_t)Hn * Dn;
  *(short4v*)(W1sT + 0 * PL + (size_t)n * Dn + k0) = s0;
  *(short4v*)(W1sT + 1 * PL + (size_t)n * Dn + k0) = s1;
  *(short4v*)(W1sT + 2 * PL + (size_t)n * Dn + k0) = s2;
}

// ---------------------------------------------------------------------------
__global__ __launch_bounds__(256, 4) void gemm_bf16x3(
    const float* __restrict__ X, const short* __restrict__ W1sT,
    double* __restrict__ Hc)
{
  // union: Abf staging (24576B)  <->  hb[16][128] f64 epilogue half (16384B)
  __shared__ __align__(16) char smem[24576];
  auto Abf = (short(*)[3][NCHUNK][2][64][8])smem;  // [buf][sp][kc][ms][lane][e]
  double* hb = (double*)smem;

  const int tid = threadIdx.x;
  const int m0  = blockIdx.x * TILE_M;

  // staging decomposition: thread -> row rA (0..31), float4 group c8 (0..7)
  const int rA    = tid >> 3;
  const int c8    = tid & 7;
  const int msT   = rA >> 4;
  const int mAT   = rA & 15;
  const int laneT = (c8 >> 1) * 16 + mAT;   // fragment lane this float4 feeds
  const int half  = c8 & 1;                 // elems 0-3 or 4-7 of the frag
  const float* Apt = X + (size_t)(m0 + rA) * Dn;

  // compute decomposition: wave w -> n-tiles {w*16, w*16+64}, m-subs {0,16}
  const int w    = tid >> 6;
  const int lane = tid & 63;
  const int mA   = lane & 15;
  const int kseg = lane >> 4;
  const int n0   = w * 16;

  // --- bf16 D-layout probe (proven): D[r][c] = r + 16*c -------------------
  int drow[4], dcol[4];
  {
    bf16x8 a, b;
    #pragma unroll
    for (int j = 0; j < 8; ++j) {
      const int k = kseg * 8 + j;
      a[j] = (short)((k == mA) ? 0x3F80 : 0);
      b[j] = (short)f2b_bits((float)(k + 16 * mA));
    }
    f32x4 z = {0.0f, 0.0f, 0.0f, 0.0f};
    z = __builtin_amdgcn_mfma_f32_16x16x32_bf16(a, b, z, 0, 0, 0);
    #pragma unroll
    for (int r = 0; r < 4; ++r) {
      const int p = (int)z[r];
      drow[r] = p & 15;
      dcol[r] = p >> 4;
    }
  }

  // accumulators: dominant stream c00 (f32 chain, f64-flushed), minor c01
  f32x4 c00[2][2], c01[2][2];
  double a64[2][2][4];
  #pragma unroll
  for (int ms = 0; ms < 2; ++ms)
    #pragma unroll
    for (int nt = 0; nt < 2; ++nt) {
      c00[ms][nt] = (f32x4){0.f, 0.f, 0.f, 0.f};
      c01[ms][nt] = (f32x4){0.f, 0.f, 0.f, 0.f};
      #pragma unroll
      for (int r = 0; r < 4; ++r) a64[ms][nt][r] = 0.0;
    }

  // B fragment base pointers (W1sT is L2-resident, 768KB)
  const size_t PL = (size_t)Hn * Dn;
  const short* bbase[3][2];
  #pragma unroll
  for (int sp = 0; sp < 3; ++sp)
    #pragma unroll
    for (int nt = 0; nt < 2; ++nt)
      bbase[sp][nt] = W1sT + sp * PL + (size_t)(n0 + nt * 64 + mA) * Dn + kseg * 8;

  // ---- X prefetch depth-2: pf[parity][j] holds sub-chunk s = loaded s ----
  float4 pf[2][2];
  #pragma unroll
  for (int j = 0; j < 2; ++j) {
    pf[0][j] = *(const float4*)(Apt + 0 * SC + 4 * (c8 + 8 * j));
    pf[1][j] = *(const float4*)(Apt + 1 * SC + 4 * (c8 + 8 * j));
  }

  // ---- B chunk-level double buffer: prologue chunk g=0 into bA -----------
  bf16x8 bA[3][2], bB[3][2];
  #pragma unroll
  for (int sp = 0; sp < 3; ++sp)
    #pragma unroll
    for (int nt = 0; nt < 2; ++nt)
      bA[sp][nt] = *(const bf16x8*)(bbase[sp][nt]);

  int buf = 0;
  for (int s = 0; s < NSUB; ++s) {
    // ---- staging: split each f32 ONCE into 3 bf16 planes, frag layout ----
    #pragma unroll
    for (int j = 0; j < 2; ++j) {
      const float xv[4] = {pf[s & 1][j].x, pf[s & 1][j].y,
                           pf[s & 1][j].z, pf[s & 1][j].w};
      short4v s0, s1, s2;
      #pragma unroll
      for (int e = 0; e < 4; ++e) {
        const unsigned u0 = f2b_bits(xv[e]); const float f0 = b_bits2f(u0);
        const float r1 = xv[e] - f0;                       // exact
        const unsigned u1 = f2b_bits(r1);    const float f1 = b_bits2f(u1);
        const float r2 = r1 - f1;                          // exact
        const unsigned u2 = f2b_bits(r2);
        s0[e] = (short)u0; s1[e] = (short)u1; s2[e] = (short)u2;
      }
      *(short4v*)&Abf[buf][0][j][msT][laneT][4 * half] = s0;
      *(short4v*)&Abf[buf][1][j][msT][laneT][4 * half] = s1;
      *(short4v*)&Abf[buf][2][j][msT][laneT][4 * half] = s2;
    }
    __syncthreads();

    // X loads for sub-chunk s+2 into the slot just freed (2-barrier distance)
    if (s + 2 < NSUB) {
      #pragma unroll
      for (int j = 0; j < 2; ++j)
        pf[s & 1][j] = *(const float4*)(Apt + (s + 2) * SC + 4 * (c8 + 8 * j));
    }

    const int g0 = s * NCHUNK;               // even chunk (uses bA)

    // ---- kc = 0: compute with bA, prefetch g0+1 into bB ------------------
    {
      #pragma unroll
      for (int sp = 0; sp < 3; ++sp)
        #pragma unroll
        for (int nt = 0; nt < 2; ++nt)
          bB[sp][nt] = *(const bf16x8*)(bbase[sp][nt] + (g0 + 1) * 32);

      #pragma unroll
      for (int ms = 0; ms < 2; ++ms) {
        const bf16x8 a0 = *(const bf16x8*)&Abf[buf][0][0][ms][lane][0];
        const bf16x8 a1 = *(const bf16x8*)&Abf[buf][1][0][ms][lane][0];
        const bf16x8 a2 = *(const bf16x8*)&Abf[buf][2][0][ms][lane][0];
        #pragma unroll
        for (int nt = 0; nt < 2; ++nt) {
          c00[ms][nt] = __builtin_amdgcn_mfma_f32_16x16x32_bf16(a0, bA[0][nt], c00[ms][nt], 0, 0, 0);
          c01[ms][nt] = __builtin_amdgcn_mfma_f32_16x16x32_bf16(a0, bA[1][nt], c01[ms][nt], 0, 0, 0);
          c01[ms][nt] = __builtin_amdgcn_mfma_f32_16x16x32_bf16(a1, bA[0][nt], c01[ms][nt], 0, 0, 0);
          c01[ms][nt] = __builtin_amdgcn_mfma_f32_16x16x32_bf16(a1, bA[1][nt], c01[ms][nt], 0, 0, 0);
          c01[ms][nt] = __builtin_amdgcn_mfma_f32_16x16x32_bf16(a0, bA[2][nt], c01[ms][nt], 0, 0, 0);
          c01[ms][nt] = __builtin_amdgcn_mfma_f32_16x16x32_bf16(a2, bA[0][nt], c01[ms][nt], 0, 0, 0);
        }
      }
      // (g0 is even -> never a flush chunk)
    }

    // ---- kc = 1: compute with bB, prefetch g0+2 into bA ------------------
    {
      if (s + 1 < NSUB) {
        #pragma unroll
        for (int sp = 0; sp < 3; ++sp)
          #pragma unroll
          for (int nt = 0; nt < 2; ++nt)
            bA[sp][nt] = *(const bf16x8*)(bbase[sp][nt] + (g0 + 2) * 32);
      }

      #pragma unroll
      for (int ms = 0; ms < 2; ++ms) {
        const bf16x8 a0 = *(const bf16x8*)&Abf[buf][0][1][ms][lane][0];
        const bf16x8 a1 = *(const bf16x8*)&Abf[buf][1][1][ms][lane][0];
        const bf16x8 a2 = *(const bf16x8*)&Abf[buf][2][1][ms][lane][0];
        #pragma unroll
        for (int nt = 0; nt < 2; ++nt) {
          c00[ms][nt] = __builtin_amdgcn_mfma_f32_16x16x32_bf16(a0, bB[0][nt], c00[ms][nt], 0, 0, 0);
          c01[ms][nt] = __builtin_amdgcn_mfma_f32_16x16x32_bf16(a0, bB[1][nt], c01[ms][nt], 0, 0, 0);
          c01[ms][nt] = __builtin_amdgcn_mfma_f32_16x16x32_bf16(a1, bB[0][nt], c01[ms][nt], 0, 0, 0);
          c01[ms][nt] = __builtin_amdgcn_mfma_f32_16x16x32_bf16(a1, bB[1][nt], c01[ms][nt], 0, 0, 0);
          c01[ms][nt] = __builtin_amdgcn_mfma_f32_16x16x32_bf16(a0, bB[2][nt], c01[ms][nt], 0, 0, 0);
          c01[ms][nt] = __builtin_amdgcn_mfma_f32_16x16x32_bf16(a2, bB[0][nt], c01[ms][nt], 0, 0, 0);
        }
      }

      // f64 flush of the dominant stream every 8 chunks (g = 7,15,23,31)
      if (((g0 + 1) & 7) == 7) {
        #pragma unroll
        for (int ms = 0; ms < 2; ++ms)
          #pragma unroll
          for (int nt = 0; nt < 2; ++nt) {
            #pragma unroll
            for (int r = 0; r < 4; ++r)
              a64[ms][nt][r] += (double)c00[ms][nt][r];
            c00[ms][nt] = (f32x4){0.f, 0.f, 0.f, 0.f};
          }
      }
    }
    buf ^= 1;
  }

  // ---- epilogue: two 16-row halves via LDS, coalesced f64 stores ---------
  #pragma unroll
  for (int ms = 0; ms < 2; ++ms) {
    __syncthreads();                 // staging reads done / prev half copied
    #pragma unroll
    for (int nt = 0; nt < 2; ++nt)
      #pragma unroll
      for (int r = 0; r < 4; ++r) {
        const double h = a64[ms][nt][r] + (double)c00[ms][nt][r] +
                         (double)c01[ms][nt][r];
        hb[drow[r] * Hn + (n0 + nt * 64 + dcol[r])] = h;
      }
    __syncthreads();
    double* dst = Hc + (size_t)(m0 + ms * 16) * Hn;
    #pragma unroll
    for (int i = tid; i < 16 * Hn / 2; i += 256)
      *(double2*)(dst + 2 * i) = *(const double2*)(hb + 2 * i);
  }
}

// ---------------------------------------------------------------------------
// Phase 2 scan v3 — UNCHANGED (proven ~10us).
// ---------------------------------------------------------------------------
constexpr int THALF = 50;

__global__ __launch_bounds__(256) void snn_scan_v3(
    const double* __restrict__ Hc, const float* __restrict__ b1,
    const float* __restrict__ W2, const float* __restrict__ b2,
    float* __restrict__ out)
{
#pragma clang fp contract(off)
  __shared__ __align__(16) double HcL[THALF * Hn];        // 51200 B
  __shared__ double W2d[Hn * Cn];                          // 5120 B
  __shared__ double Pp[Tn * Cn];                           // 4000 B
  __shared__ unsigned long long Mk[Tn][2];                 // 1600 B

  const int b   = blockIdx.x;
  const int tid = threadIdx.x;

  for (int i = tid; i < Hn * Cn; i += 256)
    W2d[i] = (double)W2[i];

  const int j0 = (tid & 63) * 2;
  const double b1a = (double)b1[j0];
  const double b1b = (double)b1[j0 + 1];
  double v1a = 0.0, v1b = 0.0;

  const double* hsrc = Hc + (size_t)b * Tn * Hn;

  for (int h = 0; h < 2; ++h) {
    if (h) __syncthreads();

    {
      const double* src = hsrc + (size_t)h * THALF * Hn;
      const int nd2 = THALF * (Hn / 2);
      int i = tid;
      for (; i + 3 * 256 < nd2; i += 4 * 256) {
        double2 a0 = *(const double2*)(src + 2 * (i + 0 * 256));
        double2 a1 = *(const double2*)(src + 2 * (i + 1 * 256));
        double2 a2 = *(const double2*)(src + 2 * (i + 2 * 256));
        double2 a3 = *(const double2*)(src + 2 * (i + 3 * 256));
        *(double2*)&HcL[2 * (i + 0 * 256)] = a0;
        *(double2*)&HcL[2 * (i + 1 * 256)] = a1;
        *(double2*)&HcL[2 * (i + 2 * 256)] = a2;
        *(double2*)&HcL[2 * (i + 3 * 256)] = a3;
      }
      for (; i < nd2; i += 256)
        *(double2*)&HcL[2 * i] = *(const double2*)(src + 2 * i);
    }
    __syncthreads();

    if (tid < 64) {
      const int lane = tid;
      double2 hnext = *(const double2*)&HcL[j0];
      for (int t = 0; t < THALF; ++t) {
        const double2 hc = hnext;
        const int tn = (t + 1 < THALF) ? (t + 1) : t;
        hnext = *(const double2*)&HcL[tn * Hn + j0];

        v1a = (v1a * D1 + hc.x) + b1a;
        v1b = (v1b * D1 + hc.y) + b1b;
        const bool ca = (v1a >= 1.0);
        const bool cb = (v1b >= 1.0);
        const unsigned long long mA = __ballot(ca);
        const unsigned long long mB = __ballot(cb);
        if (ca) v1a = 0.0;
        if (cb) v1b = 0.0;
        if (lane == 0) { Mk[h * THALF + t][0] = mA; Mk[h * THALF + t][1] = mB; }
      }
    }
  }
  __syncthreads();

  for (int pi = tid; pi < Tn * Cn; pi += 256) {
    const int tt = pi / Cn;
    const int cc = pi - tt * Cn;
    const unsigned long long mA = Mk[tt][0];
    const unsigned long long mB = Mk[tt][1];
    double sA = 0.0, sB = 0.0;
    #pragma unroll
    for (int L = 0; L < 64; ++L) {
      sA += ((mA >> L) & 1ull) ? W2d[(2 * L) * Cn + cc]     : 0.0;
      sB += ((mB >> L) & 1ull) ? W2d[(2 * L + 1) * Cn + cc] : 0.0;
    }
    Pp[pi] = sA + sB;
  }
  __syncthreads();

  if (tid < Cn) {
    const int c = tid;
    const double bb2 = (double)b2[c];
    double v2 = 0.0, acc = 0.0;
    double pn = Pp[c];
    for (int t = 0; t < Tn; ++t) {
      const double p = pn;
      const int tn = (t + 1 < Tn) ? (t + 1) : t;
      pn = Pp[tn * Cn + c];
      const double v = ((v2 * D2) + p) + bb2;
      const bool s2 = (v >= 1.0);
      v2 = s2 ? 0.0 : v;
      acc += s2 ? 1.0 : 0.0;
    }
    out[(size_t)b * Cn + c] = (float)(acc / 100.0);
  }
}

// ---------------------------------------------------------------------------
extern "C" void kernel_launch(void* const* d_in, const int* in_sizes, int n_in,
                              void* d_out, int out_size, void* d_ws, size_t ws_size,
                              hipStream_t stream) {
  const float* X  = (const float*)d_in[0];   // [B,T,D]
  const float* W1 = (const float*)d_in[1];   // [D,H]
  const float* b1 = (const float*)d_in[2];   // [H]
  const float* W2 = (const float*)d_in[3];   // [H,C]
  const float* b2 = (const float*)d_in[4];   // [C]
  float* out = (float*)d_out;                // [B,C]

  // ws = W1sT bf16 [3][128][1024] (768KB) | Hc f64 [B*Tn, H] (26.2MB)
  short*  W1sT = (short*)d_ws;
  double* Hc   = (double*)((char*)d_ws + 3u * Hn * Dn * sizeof(short));

  cvt_w1_split<<<dim3(Hn), dim3(256), 0, stream>>>(W1, W1sT);
  gemm_bf16x3<<<dim3(Bsz * Tn / TILE_M), dim3(256), 0, stream>>>(X, W1sT, Hc);
  snn_scan_v3<<<dim3(Bsz), dim3(256), 0, stream>>>(Hc, b1, W2, b2, out);
}

// Round 15
// 221.522 us; speedup vs baseline: 1.3702x; 1.3702x over previous
//
#include <hip/hip_runtime.h>

// Problem dims (fixed by the reference): B=256, T=100, D=1024, H=128, C=5
constexpr int Bsz = 256;
constexpr int Tn  = 100;
constexpr int Dn  = 1024;
constexpr int Hn  = 128;
constexpr int Cn  = 5;

// float64 values of np.exp(-1/10), np.exp(-1/20)
#define D1 0.9048374180359595731642491
#define D2 0.9512294245007140090914253

typedef short  bf16x8 __attribute__((ext_vector_type(8)));
typedef short  short4v __attribute__((ext_vector_type(4)));
typedef float  f32x4  __attribute__((ext_vector_type(4)));

// ---------------------------------------------------------------------------
// R23: fragment-order coalesced B layout on R21's proven structure.
// R22 post-mortem: launch_bounds(256,4) pinned VGPR=64, the added bA/bB/pf
// arrays SPILLED to scratch (WRITE 34->120MB, FETCH 58->74MB, gemm 165us)
// — the chunk pipeline was never really tested. Lesson: under a bounds cap,
// register arrays become scratch traffic (shows in WRITE_SIZE, not VGPR).
// R21's real stall, re-diagnosed: each of the 6 B-fragment loads per chunk
// is per-lane scattered (row stride 2KB) -> 16 distinct cache lines per
// load instruction (R19's TA-request-rate disease in miniature), inflating
// effective B latency to ~1000cy vs a ~450cy true dependency chain.
// Fix (ZERO new registers): we own W1sT's layout — pre-arrange it in
// fragment order W1F[g][sp][nt][w][lane][8] so a wave's B-fragment load is
// one fully-coalesced 1KB stream (8 sequential lines). Compute kernel is
// R21 byte-identical except the 6 bbase formulas (+g*12288 chunk stride).
// Numerics bit-identical to R21/R20 (absmax 0.0 proven).
// ---------------------------------------------------------------------------
constexpr int TILE_M = 32;
constexpr int SC     = 64;            // staging sub-chunk (k)
constexpr int NSUB   = Dn / SC;       // 16
constexpr int NCHUNK = 2;             // K=32 MFMA chunks per sub-chunk
constexpr int FRAGS  = (Dn / 32) * 3 * 2 * 4;        // 768 fragments
constexpr int CHSTR  = 3 * 2 * 4 * 512;              // 12288 shorts per chunk

__device__ __forceinline__ unsigned f2b_bits(float f) {
  union { float f; unsigned u; } c; c.f = f;
  return (c.u + 0x7FFFu + ((c.u >> 16) & 1u)) >> 16;   // RNE f32->bf16
}
__device__ __forceinline__ float b_bits2f(unsigned b) {
  union { unsigned u; float f; } c; c.u = b << 16; return c.f;
}

// ---------------------------------------------------------------------------
// W1 f32 -> fragment-order bf16 planes:
// W1F[((g*3+sp)*2+nt)*4+w][lane=kseg*16+mA][e]  (768 frags x 64 lanes x 8)
// element (k,n): g=k>>5, kseg=(k>>3)&3, e=k&7; w=(n>>4)&3, nt=(n>>6)&1, mA=n&15
// ---------------------------------------------------------------------------
__global__ __launch_bounds__(256) void cvt_w1_frag(const float* __restrict__ W1,
                                                   short* __restrict__ W1F)
{
  const int n  = blockIdx.x;              // 0..127
  const int k0 = threadIdx.x * 4;         // 0..1020 (4 consecutive k)
  const int w  = (n >> 4) & 3;
  const int nt = (n >> 6) & 1;
  const int mA = n & 15;
  const int g    = k0 >> 5;
  const int kseg = (k0 >> 3) & 3;
  const int e0   = k0 & 7;                // 0 or 4

  short4v s0, s1, s2;
  #pragma unroll
  for (int j = 0; j < 4; ++j) {
    const float x = W1[(size_t)(k0 + j) * Hn + n];
    const unsigned u0 = f2b_bits(x);  const float f0 = b_bits2f(u0);
    const float r1 = x - f0;
    const unsigned u1 = f2b_bits(r1); const float f1 = b_bits2f(u1);
    const float r2 = r1 - f1;
    const unsigned u2 = f2b_bits(r2);
    s0[j] = (short)u0; s1[j] = (short)u1; s2[j] = (short)u2;
  }
  const int lane = kseg * 16 + mA;
  #pragma unroll
  for (int sp = 0; sp < 3; ++sp) {
    const int frag = ((g * 3 + sp) * 2 + nt) * 4 + w;
    short4v* dst = (short4v*)(W1F + (size_t)frag * 512 + lane * 8 + e0);
    *dst = (sp == 0) ? s0 : (sp == 1) ? s1 : s2;
  }
}

// ---------------------------------------------------------------------------
__global__ __launch_bounds__(256, 4) void gemm_bf16x3(
    const float* __restrict__ X, const short* __restrict__ W1F,
    double* __restrict__ Hc)
{
  // union: Abf staging (24576B)  <->  hb[16][128] f64 epilogue half (16384B)
  __shared__ __align__(16) char smem[24576];
  auto Abf = (short(*)[3][NCHUNK][2][64][8])smem;  // [buf][sp][kc][ms][lane][e]
  double* hb = (double*)smem;

  const int tid = threadIdx.x;
  const int m0  = blockIdx.x * TILE_M;

  // staging decomposition: thread -> row rA (0..31), float4 group c8 (0..7)
  const int rA    = tid >> 3;
  const int c8    = tid & 7;
  const int msT   = rA >> 4;
  const int mAT   = rA & 15;
  const int laneT = (c8 >> 1) * 16 + mAT;   // fragment lane this float4 feeds
  const int half  = c8 & 1;                 // elems 0-3 or 4-7 of the frag
  const float* Apt = X + (size_t)(m0 + rA) * Dn;

  // compute decomposition: wave w -> n-tiles {w*16, w*16+64}, m-subs {0,16}
  const int w    = tid >> 6;
  const int lane = tid & 63;
  const int mA   = lane & 15;
  const int kseg = lane >> 4;
  const int n0   = w * 16;

  // --- bf16 D-layout probe (proven): D[r][c] = r + 16*c -------------------
  int drow[4], dcol[4];
  {
    bf16x8 a, b;
    #pragma unroll
    for (int j = 0; j < 8; ++j) {
      const int k = kseg * 8 + j;
      a[j] = (short)((k == mA) ? 0x3F80 : 0);
      b[j] = (short)f2b_bits((float)(k + 16 * mA));
    }
    f32x4 z = {0.0f, 0.0f, 0.0f, 0.0f};
    z = __builtin_amdgcn_mfma_f32_16x16x32_bf16(a, b, z, 0, 0, 0);
    #pragma unroll
    for (int r = 0; r < 4; ++r) {
      const int p = (int)z[r];
      drow[r] = p & 15;
      dcol[r] = p >> 4;
    }
  }

  // accumulators: dominant stream c00 (f32 chain, f64-flushed), minor c01
  f32x4 c00[2][2], c01[2][2];
  double a64[2][2][4];
  #pragma unroll
  for (int ms = 0; ms < 2; ++ms)
    #pragma unroll
    for (int nt = 0; nt < 2; ++nt) {
      c00[ms][nt] = (f32x4){0.f, 0.f, 0.f, 0.f};
      c01[ms][nt] = (f32x4){0.f, 0.f, 0.f, 0.f};
      #pragma unroll
      for (int r = 0; r < 4; ++r) a64[ms][nt][r] = 0.0;
    }

  // B fragment base pointers — fragment-order layout, lane-coalesced 16B:
  // frag(g,sp,nt,w) = ((g*3+sp)*2+nt)*4+w ; addr = frag*512 + lane*8
  const short* bbase[3][2];
  #pragma unroll
  for (int sp = 0; sp < 3; ++sp)
    #pragma unroll
    for (int nt = 0; nt < 2; ++nt)
      bbase[sp][nt] = W1F + (size_t)((sp * 2 + nt) * 4 + w) * 512 + lane * 8;

  // prefetch sub-chunk 0: 2 float4 per thread (32 m x 64 k / 256 thr)
  float4 pf[2];
  #pragma unroll
  for (int j = 0; j < 2; ++j)
    pf[j] = *(const float4*)(Apt + 4 * (c8 + 8 * j));

  int buf = 0;
  for (int s = 0; s < NSUB; ++s) {
    // ---- staging: split each f32 ONCE into 3 bf16 planes, frag layout ----
    #pragma unroll
    for (int j = 0; j < 2; ++j) {
      const float xv[4] = {pf[j].x, pf[j].y, pf[j].z, pf[j].w};
      short4v s0, s1, s2;
      #pragma unroll
      for (int e = 0; e < 4; ++e) {
        const unsigned u0 = f2b_bits(xv[e]); const float f0 = b_bits2f(u0);
        const float r1 = xv[e] - f0;                       // exact
        const unsigned u1 = f2b_bits(r1);    const float f1 = b_bits2f(u1);
        const float r2 = r1 - f1;                          // exact
        const unsigned u2 = f2b_bits(r2);
        s0[e] = (short)u0; s1[e] = (short)u1; s2[e] = (short)u2;
      }
      *(short4v*)&Abf[buf][0][j][msT][laneT][4 * half] = s0;
      *(short4v*)&Abf[buf][1][j][msT][laneT][4 * half] = s1;
      *(short4v*)&Abf[buf][2][j][msT][laneT][4 * half] = s2;
    }
    __syncthreads();

    // prefetch next sub-chunk (overlaps compute)
    if (s + 1 < NSUB) {
      #pragma unroll
      for (int j = 0; j < 2; ++j)
        pf[j] = *(const float4*)(Apt + (s + 1) * SC + 4 * (c8 + 8 * j));
    }

    #pragma unroll
    for (int kc = 0; kc < NCHUNK; ++kc) {
      const int g = s * NCHUNK + kc;           // global K=32 chunk 0..31

      // B fragments: one fully-coalesced 1KB wave-load each (L2-resident)
      bf16x8 bfr[3][2];
      #pragma unroll
      for (int sp = 0; sp < 3; ++sp)
        #pragma unroll
        for (int nt = 0; nt < 2; ++nt)
          bfr[sp][nt] = *(const bf16x8*)(bbase[sp][nt] + (size_t)g * CHSTR);

      // per m-sub: one conflict-free ds_read_b128 per plane, then 12 MFMA
      #pragma unroll
      for (int ms = 0; ms < 2; ++ms) {
        const bf16x8 a0 = *(const bf16x8*)&Abf[buf][0][kc][ms][lane][0];
        const bf16x8 a1 = *(const bf16x8*)&Abf[buf][1][kc][ms][lane][0];
        const bf16x8 a2 = *(const bf16x8*)&Abf[buf][2][kc][ms][lane][0];
        #pragma unroll
        for (int nt = 0; nt < 2; ++nt) {
          c00[ms][nt] = __builtin_amdgcn_mfma_f32_16x16x32_bf16(a0, bfr[0][nt], c00[ms][nt], 0, 0, 0);
          c01[ms][nt] = __builtin_amdgcn_mfma_f32_16x16x32_bf16(a0, bfr[1][nt], c01[ms][nt], 0, 0, 0);
          c01[ms][nt] = __builtin_amdgcn_mfma_f32_16x16x32_bf16(a1, bfr[0][nt], c01[ms][nt], 0, 0, 0);
          c01[ms][nt] = __builtin_amdgcn_mfma_f32_16x16x32_bf16(a1, bfr[1][nt], c01[ms][nt], 0, 0, 0);
          c01[ms][nt] = __builtin_amdgcn_mfma_f32_16x16x32_bf16(a0, bfr[2][nt], c01[ms][nt], 0, 0, 0);
          c01[ms][nt] = __builtin_amdgcn_mfma_f32_16x16x32_bf16(a2, bfr[0][nt], c01[ms][nt], 0, 0, 0);
        }
      }

      // f64 flush of the dominant stream every 8 chunks (same as R20/R21)
      if ((g & 7) == 7) {
        #pragma unroll
        for (int ms = 0; ms < 2; ++ms)
          #pragma unroll
          for (int nt = 0; nt < 2; ++nt) {
            #pragma unroll
            for (int r = 0; r < 4; ++r)
              a64[ms][nt][r] += (double)c00[ms][nt][r];
            c00[ms][nt] = (f32x4){0.f, 0.f, 0.f, 0.f};
          }
      }
    }
    buf ^= 1;
  }

  // ---- epilogue: two 16-row halves via LDS, coalesced f64 stores ---------
  #pragma unroll
  for (int ms = 0; ms < 2; ++ms) {
    __syncthreads();                 // staging reads done / prev half copied
    #pragma unroll
    for (int nt = 0; nt < 2; ++nt)
      #pragma unroll
      for (int r = 0; r < 4; ++r) {
        const double h = a64[ms][nt][r] + (double)c00[ms][nt][r] +
                         (double)c01[ms][nt][r];
        hb[drow[r] * Hn + (n0 + nt * 64 + dcol[r])] = h;
      }
    __syncthreads();
    double* dst = Hc + (size_t)(m0 + ms * 16) * Hn;
    #pragma unroll
    for (int i = tid; i < 16 * Hn / 2; i += 256)
      *(double2*)(dst + 2 * i) = *(const double2*)(hb + 2 * i);
  }
}

// ---------------------------------------------------------------------------
// Phase 2 scan v3 — UNCHANGED (proven ~10us).
// ---------------------------------------------------------------------------
constexpr int THALF = 50;

__global__ __launch_bounds__(256) void snn_scan_v3(
    const double* __restrict__ Hc, const float* __restrict__ b1,
    const float* __restrict__ W2, const float* __restrict__ b2,
    float* __restrict__ out)
{
#pragma clang fp contract(off)
  __shared__ __align__(16) double HcL[THALF * Hn];        // 51200 B
  __shared__ double W2d[Hn * Cn];                          // 5120 B
  __shared__ double Pp[Tn * Cn];                           // 4000 B
  __shared__ unsigned long long Mk[Tn][2];                 // 1600 B

  const int b   = blockIdx.x;
  const int tid = threadIdx.x;

  for (int i = tid; i < Hn * Cn; i += 256)
    W2d[i] = (double)W2[i];

  const int j0 = (tid & 63) * 2;
  const double b1a = (double)b1[j0];
  const double b1b = (double)b1[j0 + 1];
  double v1a = 0.0, v1b = 0.0;

  const double* hsrc = Hc + (size_t)b * Tn * Hn;

  for (int h = 0; h < 2; ++h) {
    if (h) __syncthreads();

    {
      const double* src = hsrc + (size_t)h * THALF * Hn;
      const int nd2 = THALF * (Hn / 2);
      int i = tid;
      for (; i + 3 * 256 < nd2; i += 4 * 256) {
        double2 a0 = *(const double2*)(src + 2 * (i + 0 * 256));
        double2 a1 = *(const double2*)(src + 2 * (i + 1 * 256));
        double2 a2 = *(const double2*)(src + 2 * (i + 2 * 256));
        double2 a3 = *(const double2*)(src + 2 * (i + 3 * 256));
        *(double2*)&HcL[2 * (i + 0 * 256)] = a0;
        *(double2*)&HcL[2 * (i + 1 * 256)] = a1;
        *(double2*)&HcL[2 * (i + 2 * 256)] = a2;
        *(double2*)&HcL[2 * (i + 3 * 256)] = a3;
      }
      for (; i < nd2; i += 256)
        *(double2*)&HcL[2 * i] = *(const double2*)(src + 2 * i);
    }
    __syncthreads();

    if (tid < 64) {
      const int lane = tid;
      double2 hnext = *(const double2*)&HcL[j0];
      for (int t = 0; t < THALF; ++t) {
        const double2 hc = hnext;
        const int tn = (t + 1 < THALF) ? (t + 1) : t;
        hnext = *(const double2*)&HcL[tn * Hn + j0];

        v1a = (v1a * D1 + hc.x) + b1a;
        v1b = (v1b * D1 + hc.y) + b1b;
        const bool ca = (v1a >= 1.0);
        const bool cb = (v1b >= 1.0);
        const unsigned long long mA = __ballot(ca);
        const unsigned long long mB = __ballot(cb);
        if (ca) v1a = 0.0;
        if (cb) v1b = 0.0;
        if (lane == 0) { Mk[h * THALF + t][0] = mA; Mk[h * THALF + t][1] = mB; }
      }
    }
  }
  __syncthreads();

  for (int pi = tid; pi < Tn * Cn; pi += 256) {
    const int tt = pi / Cn;
    const int cc = pi - tt * Cn;
    const unsigned long long mA = Mk[tt][0];
    const unsigned long long mB = Mk[tt][1];
    double sA = 0.0, sB = 0.0;
    #pragma unroll
    for (int L = 0; L < 64; ++L) {
      sA += ((mA >> L) & 1ull) ? W2d[(2 * L) * Cn + cc]     : 0.0;
      sB += ((mB >> L) & 1ull) ? W2d[(2 * L + 1) * Cn + cc] : 0.0;
    }
    Pp[pi] = sA + sB;
  }
  __syncthreads();

  if (tid < Cn) {
    const int c = tid;
    const double bb2 = (double)b2[c];
    double v2 = 0.0, acc = 0.0;
    double pn = Pp[c];
    for (int t = 0; t < Tn; ++t) {
      const double p = pn;
      const int tn = (t + 1 < Tn) ? (t + 1) : t;
      pn = Pp[tn * Cn + c];
      const double v = ((v2 * D2) + p) + bb2;
      const bool s2 = (v >= 1.0);
      v2 = s2 ? 0.0 : v;
      acc += s2 ? 1.0 : 0.0;
    }
    out[(size_t)b * Cn + c] = (float)(acc / 100.0);
  }
}

// ---------------------------------------------------------------------------
extern "C" void kernel_launch(void* const* d_in, const int* in_sizes, int n_in,
                              void* d_out, int out_size, void* d_ws, size_t ws_size,
                              hipStream_t stream) {
  const float* X  = (const float*)d_in[0];   // [B,T,D]
  const float* W1 = (const float*)d_in[1];   // [D,H]
  const float* b1 = (const float*)d_in[2];   // [H]
  const float* W2 = (const float*)d_in[3];   // [H,C]
  const float* b2 = (const float*)d_in[4];   // [C]
  float* out = (float*)d_out;                // [B,C]

  // ws = W1F bf16 frag-order [768][64][8] (768KB) | Hc f64 [B*Tn, H] (26.2MB)
  short*  W1F = (short*)d_ws;
  double* Hc  = (double*)((char*)d_ws + (size_t)FRAGS * 512 * sizeof(short));

  cvt_w1_frag<<<dim3(Hn), dim3(256), 0, stream>>>(W1, W1F);
  gemm_bf16x3<<<dim3(Bsz * Tn / TILE_M), dim3(256), 0, stream>>>(X, W1F, Hc);
  snn_scan_v3<<<dim3(Bsz), dim3(256), 0, stream>>>(Hc, b1, W2, b2, out);
}